// Round 5
// baseline (217.467 us; speedup 1.0000x reference)
//
#include <hip/hip_runtime.h>

// Banded stereo cost volume via MFMA, all 3 scales in ONE launch.
// cost[j,h,x] = sum_c L[c,h,x]*R[c,h,x-j], 0 if x<j. C=32.
//
// Round-9: MFMA rewrite. The op IS a banded GEMM: per h, C[x,x'] = sum_c
// L[c,x]*R[c,x'] restricted to 0 <= x-x' <= D-1, with out[j,h,x]=C[x,x-j].
// K = 32 = one v_mfma_f32_16x16x32_f16 per 16x16 tile (no K loop).
// Rounds 6-8 showed the VALU-FMA path stuck at ~58us vs a ~26us HBM floor
// (VALU ~11us + LDS ~23us partially serialized); MFMA removes both pipes.
// f16 inputs are fine: threshold is bf16-grade (0.725), predicted err <~0.05.
//
// Per block: 1 h, 128 x (8 m-tiles). 4 waves; wave w owns m-tiles q0=2w,
// q0+1. R staged for x' in [x0-192, x0+127] (320 rows, zero-pad x'<0 ->
// band zeros fall out of the matmul free). Per m-tile q: n-tiles q..q+12
// (13 accs); wave total 26 mfma, 104 acc VGPRs.
// k-permutation invariance: A and B frags use the SAME lane->k rule
// (8 contiguous c at chunk l>>4), so the exact hw k-mapping cancels;
// C/D layout is the verified col=lane&15, row=(lane>>4)*4+reg.
// Staging LDS: f16 [row][32 c] 64B rows, chunk-XOR swizzle (^(row>>1)&3)
// -> 2-way (free) on both b64 staging writes and b128 frag reads.
// Epilogue: per-wave private sliding window (2 tiles per m-tile) in LDS;
// j-group steps emit full 128B-line stores (8 lanes x 16B contiguous).

#define NBLK_TOTAL 1344

typedef float vf4 __attribute__((ext_vector_type(4)));
typedef float f32x4 __attribute__((ext_vector_type(4)));
typedef _Float16 h4 __attribute__((ext_vector_type(4)));
typedef _Float16 h8 __attribute__((ext_vector_type(8)));

__global__ __launch_bounds__(256, 3)
void cost_volume_fused(const float* __restrict__ L0, const float* __restrict__ R0,
                       const float* __restrict__ L1, const float* __restrict__ R1,
                       const float* __restrict__ L2, const float* __restrict__ R2,
                       float* __restrict__ out)
{
    // Staging: 448 rows (L: 0..127 = x-x0; R: 128..447 = x'-(x0-192)) x 64 B.
    __shared__ __align__(16) unsigned short St[448 * 32];   // 28 KB f16
    __shared__ __align__(16) float Ep[4 * 1024];            // 16 KB, 4 KB/wave

    const int id = blockIdx.x;
    const float* L; const float* R; float* o;
    int H, W, D, bx, h;
    if (id < 1024) {            // scale 0: H=256 W=512 D=192
        L = L0; R = R0; o = out;
        H = 256; W = 512; D = 192;
        bx = id & 3; h = id >> 2;
    } else if (id < 1280) {     // scale 1: H=128 W=256 D=96
        int r = id - 1024;
        L = L1; R = R1; o = out + (size_t)192 * 256 * 512;
        H = 128; W = 256; D = 96;
        bx = r & 1; h = r >> 1;
    } else {                    // scale 2: H=64 W=128 D=48
        int r = id - 1280;
        L = L2; R = R2; o = out + (size_t)192 * 256 * 512 + (size_t)96 * 128 * 256;
        H = 64; W = 128; D = 48;
        bx = 0; h = r;
    }

    const int x0 = bx * 128;
    const int t  = threadIdx.x;
    const int l  = t & 63;
    const int w_ = t >> 6;

    const size_t HW = (size_t)H * W;
    const float* Lb = L + (size_t)h * W;
    const float* Rb = R + (size_t)h * W;

    char* Sb = (char*)St;

    // ---- stage L: 256 items = (c4, x4); 4x4 reg transpose, f32 -> f16 ----
    {
        const int c0 = (t >> 5) * 4;
        const int x4 = t & 31;
        const float* gp = Lb + (size_t)c0 * HW + x0 + 4 * x4;
        vf4 v0 = *(const vf4*)(gp);
        vf4 v1 = *(const vf4*)(gp + HW);
        vf4 v2 = *(const vf4*)(gp + 2 * HW);
        vf4 v3 = *(const vf4*)(gp + 3 * HW);
        #pragma unroll
        for (int xi = 0; xi < 4; ++xi) {
            int row = 4 * x4 + xi;
            h4 hv = { (_Float16)v0[xi], (_Float16)v1[xi],
                      (_Float16)v2[xi], (_Float16)v3[xi] };
            *(h4*)(Sb + row * 64 + ((((c0 >> 3) ^ ((row >> 1) & 3)) << 4)
                                    | ((c0 & 7) << 1))) = hv;
        }
    }
    // ---- stage R: 640 items; x' = x0-192+4*x4; x'<0 rows = 0 ----
    #pragma unroll
    for (int k = 0; k < 3; ++k) {
        int idm = t + k * 256;
        if (idm < 640) {
            int c0 = (idm / 80) * 4;
            int x4 = idm - (idm / 80) * 80;
            int g = x0 - 192 + 4 * x4;
            vf4 v0 = (vf4)(0.f), v1 = (vf4)(0.f), v2 = (vf4)(0.f), v3 = (vf4)(0.f);
            if (g >= 0) {   // g+3 <= x0+127 <= W-1 always
                const float* gp = Rb + (size_t)c0 * HW + g;
                v0 = *(const vf4*)(gp);
                v1 = *(const vf4*)(gp + HW);
                v2 = *(const vf4*)(gp + 2 * HW);
                v3 = *(const vf4*)(gp + 3 * HW);
            }
            #pragma unroll
            for (int xi = 0; xi < 4; ++xi) {
                int row = 128 + 4 * x4 + xi;
                h4 hv = { (_Float16)v0[xi], (_Float16)v1[xi],
                          (_Float16)v2[xi], (_Float16)v3[xi] };
                *(h4*)(Sb + row * 64 + ((((c0 >> 3) ^ ((row >> 1) & 3)) << 4)
                                        | ((c0 & 7) << 1))) = hv;
            }
        }
    }
    __syncthreads();

    // ---- MFMA: wave w -> m-tiles q0=2w, q0+1; n-tiles q..q+12 each ----
    const int lm = l & 15;
    const int kg = l >> 4;
    const int q0 = 2 * w_;

    f32x4 acc0[13], acc1[13];
    #pragma unroll
    for (int i = 0; i < 13; ++i) { acc0[i] = (f32x4)(0.f); acc1[i] = (f32x4)(0.f); }

    const int rowA0 = 16 * q0 + lm;
    const int rowA1 = rowA0 + 16;
    h8 a0 = *(const h8*)(Sb + rowA0 * 64 + ((kg ^ ((rowA0 >> 1) & 3)) << 4));
    h8 a1 = *(const h8*)(Sb + rowA1 * 64 + ((kg ^ ((rowA1 >> 1) & 3)) << 4));

    #pragma unroll
    for (int nt = 0; nt <= 13; ++nt) {
        int rowB = 128 + 16 * (q0 + nt) + lm;
        h8 b = *(const h8*)(Sb + rowB * 64 + ((kg ^ ((rowB >> 1) & 3)) << 4));
        if (nt <= 12)
            acc0[nt] = __builtin_amdgcn_mfma_f32_16x16x32_f16(a0, b, acc0[nt], 0, 0, 0);
        if (nt >= 1)
            acc1[nt - 1] = __builtin_amdgcn_mfma_f32_16x16x32_f16(a1, b, acc1[nt - 1], 0, 0, 0);
    }

    // ---- epilogue: per-wave private sliding window; no barriers needed ----
    // Tile (mt, rel) lives at slot rel&1. Step jg uses rel 12-jg (hi, written
    // previous step) and 11-jg (lo, written this step). j-rows then stored as
    // full 128-B lines: round r: j = 16jg+8r+(l>>3), x covers 128 x per wave.
    float* Cw = Ep + w_ * 1024;
    const int Dg = D >> 4;      // 12, 6, 3

    #pragma unroll
    for (int jg = 0; jg < 12; ++jg) {
        if (jg >= Dg) break;
        {   // write tile(s): rel = 11-jg (both mt); at jg==0 also rel = 12
            #pragma unroll
            for (int e = 0; e < 2; ++e) {
                int rel = (e == 0) ? (11 - jg) : 12;
                if (e == 1 && jg != 0) break;
                f32x4 ta = acc0[rel];
                f32x4 tb = acc1[rel];
                float* b0 = Cw + (0 * 2 + (rel & 1)) * 256;
                float* b1 = Cw + (1 * 2 + (rel & 1)) * 256;
                #pragma unroll
                for (int rr = 0; rr < 4; ++rr) {
                    int m = kg * 4 + rr;
                    int off = m * 16 + (lm ^ ((m >> 2) << 2));
                    b0[off] = ta[rr];
                    b1[off] = tb[rr];
                }
            }
        }
        #pragma unroll
        for (int r = 0; r < 2; ++r) {
            int j  = 16 * jg + 8 * r + (l >> 3);
            int xbl = (l & 7) * 4;          // x_loc base; 4-run never crosses mt
            int mt = xbl >> 4;
            f32x4 v;
            #pragma unroll
            for (int i = 0; i < 4; ++i) {
                int xl = xbl + i;
                int m = xl & 15;
                int xp = 32 * w_ + xl + 192 - j;      // x' - (x0-192), >= 1
                int rel = (xp >> 4) - (q0 + mt);      // in {11-jg, 12-jg}
                int n = xp & 15;
                v[i] = Cw[(mt * 2 + (rel & 1)) * 256 + m * 16 + (n ^ ((m >> 2) << 2))];
            }
            float* p = o + ((size_t)j * H + h) * W + x0 + 32 * w_ + xbl;
            __builtin_nontemporal_store(*(vf4*)&v, (vf4*)p);
        }
    }
}

extern "C" void kernel_launch(void* const* d_in, const int* in_sizes, int n_in,
                              void* d_out, int out_size, void* d_ws, size_t ws_size,
                              hipStream_t stream)
{
    const float* L0 = (const float*)d_in[0];
    const float* R0 = (const float*)d_in[1];
    const float* L1 = (const float*)d_in[2];
    const float* R1 = (const float*)d_in[3];
    const float* L2 = (const float*)d_in[4];
    const float* R2 = (const float*)d_in[5];
    float* out = (float*)d_out;

    cost_volume_fused<<<dim3(NBLK_TOTAL), dim3(256), 0, stream>>>(
        L0, R0, L1, R1, L2, R2, out);
}